// Round 3
// baseline (45.133 us; speedup 1.0000x reference)
//
#include <hip/hip_runtime.h>
#include <math.h>

#define EPSF 1e-20f
#define HH 256
#define HP 128
#define XP 41              // LDS x-tile pitch (odd -> bank spread)
#define NEG_INF (-INFINITY)

__device__ __forceinline__ float softplusf(float x) {
    return fmaxf(x, 0.0f) + log1pf(expf(-fabsf(x)));
}

// One block = one 64x64 output tile of one (b,c) plane.
// Phase 1: 34x34 x-tile (x1 = cs_prop*s_prop, x2 = cs_prop) incl. halo -> LDS.
// Phase 2: 4-tap transposed depthwise conv + fused epilogue from LDS.
__global__ __launch_bounds__(256) void fused_sndeconv(
    const float* __restrict__ d, const float* __restrict__ cd,
    const float* __restrict__ s, const float* __restrict__ cs,
    const float* __restrict__ w_s_from_d, const float* __restrict__ w_prop,
    const float* __restrict__ spatial_weight, const float* __restrict__ bias,
    float* __restrict__ s_out, float* __restrict__ cs_out)
{
    __shared__ float lx1[34][XP];
    __shared__ float lx2[34][XP];
    __shared__ float sws[16];

    const int blk = blockIdx.x;
    const int bc  = blk >> 4;
    const int ty  = (blk >> 2) & 3;
    const int tx  = blk & 3;
    const int c   = bc & 15;
    const int mb  = 32 * ty, nb = 32 * tx;
    const int tid = threadIdx.x;

    if (tid < 16) sws[tid] = softplusf(spatial_weight[c * 16 + tid]);

    const float* dp  = d  + (size_t)bc * (HH * HH);
    const float* cdp = cd + (size_t)bc * (HH * HH);
    const float* sp  = s  + (size_t)bc * (HP * HP);
    const float* csp = cs + (size_t)bc * (HP * HP);

    const float a0 = w_s_from_d[0];
    const float a1 = w_s_from_d[1];
    const float wp = softplusf(w_prop[0]);

    // ---------------- phase 1: build x-tile ----------------
    // units: per x-row a (34), u=0 single (b=0), u=1..16 pairs (b=2k+1,2k+2), u=17 single (b=33)
    for (int it = 0; it < 3; ++it) {
        int unit = tid + 256 * it;
        if (unit >= 612) break;
        int a = unit / 18;
        int u = unit - a * 18;
        int m = mb - 1 + a;

        if (m < 0 || m > 127) {                 // padding row -> zeros
            if (u == 0)       { lx1[a][0]  = 0.f; lx2[a][0]  = 0.f; }
            else if (u == 17) { lx1[a][33] = 0.f; lx2[a][33] = 0.f; }
            else { int b = 2*(u-1)+1;
                   lx1[a][b] = 0.f; lx1[a][b+1] = 0.f;
                   lx2[a][b] = 0.f; lx2[a][b+1] = 0.f; }
            continue;
        }
        int r0 = 2 * m - 1;

        if (u == 0 || u == 17) {                // single halo column
            int n = (u == 0) ? (nb - 1) : (nb + 32);
            int b = (u == 0) ? 0 : 33;
            if (n < 0 || n > 127) { lx1[a][b] = 0.f; lx2[a][b] = 0.f; continue; }
            // window cols 2n-1..2n+2 are always in-bounds for valid n here
            int cb0 = 2 * n - 1;
            float b1 = NEG_INF, dmx = 0.f, cmx = 0.f;
            float b2 = NEG_INF, dmn = 0.f, cmn = 0.f;
            #pragma unroll
            for (int kh = 0; kh < 4; ++kh) {
                int r  = r0 + kh;
                int rl = r < 0 ? 0 : (r > 255 ? 255 : r);
                bool rv = (r >= 0) && (r < 256);
                const float* drow = dp  + rl * 256;
                const float* crow = cdp + rl * 256;
                #pragma unroll
                for (int idx = 0; idx < 4; ++idx) {
                    float dv = drow[cb0 + idx];
                    float cv = crow[cb0 + idx];
                    float v1 = rv ? dv * cv          : NEG_INF;
                    float v2 = rv ? cv / (dv + EPSF) : NEG_INF;
                    bool w1 = v1 > b1; b1 = w1 ? v1 : b1; dmx = w1 ? dv : dmx; cmx = w1 ? cv : cmx;
                    bool w2 = v2 > b2; b2 = w2 ? v2 : b2; dmn = w2 ? dv : dmn; cmn = w2 ? cv : cmn;
                }
            }
            float sv  = sp[m * 128 + n];
            float csv = csp[m * 128 + n];
            float mm_  = fabsf(dmn / (dmx + EPSF));
            float sfd  = (1.0f - a0 - a1) * mm_ + a0 * mm_ * mm_ + a1 * mm_ * mm_ * mm_;
            float csfd = cmx * cmn;
            float den  = wp * csv + csfd;
            float spv  = (wp * csv * sv + csfd * sfd) / (den + EPSF);
            float cp   = den / (wp + 1.0f);
            lx1[a][b] = cp * spv;
            lx2[a][b] = cp;
            continue;
        }

        // pair unit: outputs n = nL (even), nL+1 ; shared 4x6 window
        int k  = u - 1;
        int nL = nb + 2 * k;
        int cb = 2 * nL;                        // multiple of 4
        int c_lo = (cb - 1 < 0) ? 0 : cb - 1;
        int c_hi = (cb + 4 > 255) ? 255 : cb + 4;
        bool has_lo = (cb >= 1);
        bool has_hi = (cb + 4 <= 255);

        float bA1 = NEG_INF, dA1 = 0.f, cA1 = 0.f;
        float bA2 = NEG_INF, dA2 = 0.f, cA2 = 0.f;
        float bB1 = NEG_INF, dB1 = 0.f, cB1 = 0.f;
        float bB2 = NEG_INF, dB2 = 0.f, cB2 = 0.f;

        #pragma unroll
        for (int kh = 0; kh < 4; ++kh) {
            int r  = r0 + kh;
            int rl = r < 0 ? 0 : (r > 255 ? 255 : r);
            bool rv = (r >= 0) && (r < 256);
            const float* drow = dp  + rl * 256;
            const float* crow = cdp + rl * 256;
            float4 d4 = *(const float4*)(drow + cb);
            float4 c4 = *(const float4*)(crow + cb);
            float wd[6] = { drow[c_lo], d4.x, d4.y, d4.z, d4.w, drow[c_hi] };
            float wc[6] = { crow[c_lo], c4.x, c4.y, c4.z, c4.w, crow[c_hi] };
            bool  mv[6] = { rv && has_lo, rv, rv, rv, rv, rv && has_hi };
            #pragma unroll
            for (int idx = 0; idx < 6; ++idx) {
                float v1 = mv[idx] ? wd[idx] * wc[idx]          : NEG_INF;
                float v2 = mv[idx] ? wc[idx] / (wd[idx] + EPSF) : NEG_INF;
                if (idx <= 3) {
                    bool u1 = v1 > bA1;
                    bA1 = u1 ? v1 : bA1; dA1 = u1 ? wd[idx] : dA1; cA1 = u1 ? wc[idx] : cA1;
                    bool u2 = v2 > bA2;
                    bA2 = u2 ? v2 : bA2; dA2 = u2 ? wd[idx] : dA2; cA2 = u2 ? wc[idx] : cA2;
                }
                if (idx >= 2) {
                    bool u1 = v1 > bB1;
                    bB1 = u1 ? v1 : bB1; dB1 = u1 ? wd[idx] : dB1; cB1 = u1 ? wc[idx] : cB1;
                    bool u2 = v2 > bB2;
                    bB2 = u2 ? v2 : bB2; dB2 = u2 ? wd[idx] : dB2; cB2 = u2 ? wc[idx] : cB2;
                }
            }
        }

        float2 sv2  = *(const float2*)(sp  + m * 128 + nL);
        float2 csv2 = *(const float2*)(csp + m * 128 + nL);

        float mA   = fabsf(dA2 / (dA1 + EPSF));
        float sfdA  = (1.0f - a0 - a1) * mA + a0 * mA * mA + a1 * mA * mA * mA;
        float csfdA = cA1 * cA2;
        float denA  = wp * csv2.x + csfdA;
        float spA   = (wp * csv2.x * sv2.x + csfdA * sfdA) / (denA + EPSF);
        float cpA   = denA / (wp + 1.0f);

        float mB   = fabsf(dB2 / (dB1 + EPSF));
        float sfdB  = (1.0f - a0 - a1) * mB + a0 * mB * mB + a1 * mB * mB * mB;
        float csfdB = cB1 * cB2;
        float denB  = wp * csv2.y + csfdB;
        float spB   = (wp * csv2.y * sv2.y + csfdB * sfdB) / (denB + EPSF);
        float cpB   = denB / (wp + 1.0f);

        int bL = 2 * k + 1;
        lx1[a][bL]     = cpA * spA;
        lx1[a][bL + 1] = cpB * spB;
        lx2[a][bL]     = cpA;
        lx2[a][bL + 1] = cpB;
    }

    __syncthreads();

    // ---------------- phase 2: deconv + epilogue ----------------
    int ii = tid >> 2, jq = tid & 3;
    int i  = 64 * ty + ii;
    int u0 = (i + 1) & 1;
    int m0 = (i + 1 - u0) >> 1;
    int ar = m0 - mb + 1;                       // 1..33
    float rv0 = (m0 <= 127) ? 1.f : 0.f;
    float rv1 = (m0 >= 1)   ? 1.f : 0.f;

    float wA0 = sws[u0*4 + 0], wA1 = sws[u0*4 + 1], wA2 = sws[u0*4 + 2], wA3 = sws[u0*4 + 3];
    float wC0 = sws[(u0+2)*4 + 0], wC1 = sws[(u0+2)*4 + 1], wC2 = sws[(u0+2)*4 + 2], wC3 = sws[(u0+2)*4 + 3];
    float bv  = bias[c];

    int bb = 8 * jq;                            // x-tile col base (b index)
    float r1a[10], r1b[10], r2a[10], r2b[10];
    #pragma unroll
    for (int rn = 0; rn < 10; ++rn) {
        r1a[rn] = lx1[ar][bb + rn];
        r1b[rn] = lx1[ar - 1][bb + rn];
        r2a[rn] = lx2[ar][bb + rn];
        r2b[rn] = lx2[ar - 1][bb + rn];
    }

    int jbase = 64 * tx + 16 * jq;
    int n0b   = 32 * tx + 8 * jq;               // n0(e) = n0b + (e+1)/2
    size_t orow = (size_t)bc * (HH * HH) + (size_t)i * HH + jbase;

    float so[4], co[4];
    #pragma unroll
    for (int e = 0; e < 16; ++e) {
        const int v0 = (e + 1) & 1;
        const int hi = 1 + ((e + 1) >> 1);      // reg idx of tap n0
        const int lo = hi - 1;                  // reg idx of tap n0-1
        float swa = v0 ? wA1 : wA0;             // (u0,   v0)
        float swb = v0 ? wA3 : wA2;             // (u0,   v0+2)
        float swc = v0 ? wC1 : wC0;             // (u0+2, v0)
        float swd = v0 ? wC3 : wC2;             // (u0+2, v0+2)

        float nom = swa*r1a[hi] + swb*r1a[lo] + swc*r1b[hi] + swd*r1b[lo];
        float den = swa*r2a[hi] + swb*r2a[lo] + swc*r2b[hi] + swd*r2b[lo];

        int n0 = n0b + ((e + 1) >> 1);
        float nvh = (n0 <= 127) ? 1.f : 0.f;
        float nvl = (n0 >= 1)   ? 1.f : 0.f;
        float cden = rv0 * (swa*nvh + swb*nvl) + rv1 * (swc*nvh + swd*nvl);

        so[e & 3] = nom / (den + EPSF) + bv;
        co[e & 3] = den / cden;
        if ((e & 3) == 3) {
            *(float4*)(s_out  + orow + (e - 3)) = make_float4(so[0], so[1], so[2], so[3]);
            *(float4*)(cs_out + orow + (e - 3)) = make_float4(co[0], co[1], co[2], co[3]);
        }
    }
}

extern "C" void kernel_launch(void* const* d_in, const int* in_sizes, int n_in,
                              void* d_out, int out_size, void* d_ws, size_t ws_size,
                              hipStream_t stream) {
    const float* d    = (const float*)d_in[0];
    const float* cd   = (const float*)d_in[1];
    const float* s    = (const float*)d_in[2];
    const float* cs   = (const float*)d_in[3];
    const float* wsd  = (const float*)d_in[4];
    const float* wpr  = (const float*)d_in[5];
    const float* spw  = (const float*)d_in[6];
    const float* bias = (const float*)d_in[7];

    float* out   = (float*)d_out;
    float* s_o   = out;
    float* cs_o  = out + (size_t)4 * 16 * HH * HH;

    // 64 planes x 16 tiles (4x4 of 64x64 outputs) = 1024 blocks
    fused_sndeconv<<<1024, 256, 0, stream>>>(d, cd, s, cs, wsd, wpr, spw, bias, s_o, cs_o);
}

// Round 4
// 35.391 us; speedup vs baseline: 1.2752x; 1.2752x over previous
//
#include <hip/hip_runtime.h>
#include <math.h>

#define EPSF 1e-20f
#define NEG_INF (-INFINITY)

__device__ __forceinline__ float softplusf(float x) {
    return fmaxf(x, 0.0f) + log1pf(expf(-fabsf(x)));
}

// One block = 32x64 output tile of one (b,c) plane. 2048 blocks.
// Stage B: horizontal 4-col dual argmax per (input row, x-col) -> W LDS (val+idx per chain).
// Stage C: vertical 4-row combine + gather + propagation math -> lx LDS.
// Stage D: 4-tap transposed depthwise conv + fused epilogue.
__global__ __launch_bounds__(256) void fused_sndeconv(
    const float* __restrict__ d, const float* __restrict__ cd,
    const float* __restrict__ s, const float* __restrict__ cs,
    const float* __restrict__ w_s_from_d, const float* __restrict__ w_prop,
    const float* __restrict__ spatial_weight, const float* __restrict__ bias,
    float* __restrict__ s_out, float* __restrict__ cs_out)
{
    __shared__ uint4 W[38][35];          // (val1,idx1,val2,idx2) per (row, x-col); 21.3 KB
    __shared__ float lx1[18][36];        // x1 tile (16B-aligned rows); 2.6 KB
    __shared__ float lx2[18][36];
    __shared__ float sws[16];

    const int tid = threadIdx.x;
    const int blk = blockIdx.x;
    const int bc  = blk >> 5;            // plane 0..63
    const int tl  = blk & 31;
    const int by  = tl >> 2;             // 0..7  (32-row bands)
    const int bx  = tl & 3;              // 0..3  (64-col bands)
    const int c   = bc & 15;

    const int ib = by << 5;              // output row base
    const int jb = bx << 6;              // output col base
    const int mB = (ib >> 1) - 1;        // x-row base   (18 rows: mB..mB+17)
    const int nB = (jb >> 1) - 1;        // x-col base   (34 cols: nB..nB+33)
    const int rB = 2 * mB - 1;           // input row base (38 rows)
    const int cB = 2 * nB - 1;           // input col base of idx0

    if (tid < 16) sws[tid] = softplusf(spatial_weight[c * 16 + tid]);

    const float* dp  = d  + (size_t)bc * 65536;
    const float* cdp = cd + (size_t)bc * 65536;
    const float* sp  = s  + (size_t)bc * 16384;
    const float* csp = cs + (size_t)bc * 16384;

    const float a0 = w_s_from_d[0];
    const float a1 = w_s_from_d[1];
    const float wp = softplusf(w_prop[0]);

    // ---------------- stage B: horizontal window argmax ----------------
    #pragma unroll
    for (int it = 0; it < 6; ++it) {
        int unit = tid + 256 * it;
        if (unit < 1292) {
            int wr = unit / 34;
            int wn = unit - wr * 34;
            int r  = rB + wr;
            int cb = cB + 2 * wn;                    // col of window idx0
            bool rv = (r >= 0) && (r < 256);
            int  rl = r < 0 ? 0 : (r > 255 ? 255 : r);
            const float* drow = dp  + rl * 256;
            const float* crow = cdp + rl * 256;

            int c0 = cb < 0 ? 0 : cb;
            int c3 = (cb + 3 > 255) ? 255 : cb + 3;
            int cm = cb + 1; cm = cm < 0 ? 0 : (cm > 254 ? 254 : cm);  // even, aligned
            float2 dm = *(const float2*)(drow + cm);
            float2 cc = *(const float2*)(crow + cm);
            float wd[4] = { drow[c0], dm.x, dm.y, drow[c3] };
            float wc[4] = { crow[c0], cc.x, cc.y, crow[c3] };

            float b1 = NEG_INF, b2 = NEG_INF;
            int   i1 = 0,       i2 = 0;
            #pragma unroll
            for (int k = 0; k < 4; ++k) {
                int  ck = cb + k;
                bool mv = rv && (ck >= 0) && (ck < 256);
                float v1 = mv ? wd[k] * wc[k]          : NEG_INF;
                float v2 = mv ? wc[k] / (wd[k] + EPSF) : NEG_INF;
                int  fi = rl * 256 + (ck < 0 ? 0 : (ck > 255 ? 255 : ck));
                bool t1 = v1 > b1; b1 = t1 ? v1 : b1; i1 = t1 ? fi : i1;
                bool t2 = v2 > b2; b2 = t2 ? v2 : b2; i2 = t2 ? fi : i2;
            }
            uint4 w;
            w.x = __float_as_uint(b1); w.y = (unsigned)i1;
            w.z = __float_as_uint(b2); w.w = (unsigned)i2;
            W[wr][wn] = w;
        }
    }
    __syncthreads();

    // ---------------- stage C: vertical combine + prop math ----------------
    #pragma unroll
    for (int it = 0; it < 3; ++it) {
        int unit = tid + 256 * it;
        if (unit < 612) {
            int cmr = unit / 34;
            int cn  = unit - cmr * 34;
            int m   = mB + cmr;
            int n   = nB + cn;
            if (m < 0 || m > 127 || n < 0 || n > 127) {
                lx1[cmr][cn] = 0.f;
                lx2[cmr][cn] = 0.f;
            } else {
                uint4 w0 = W[2 * cmr + 0][cn];
                uint4 w1 = W[2 * cmr + 1][cn];
                uint4 w2 = W[2 * cmr + 2][cn];
                uint4 w3 = W[2 * cmr + 3][cn];

                float b1 = __uint_as_float(w0.x); int i1 = (int)w0.y;
                float b2 = __uint_as_float(w0.z); int i2 = (int)w0.w;
                {
                    float v = __uint_as_float(w1.x); bool t = v > b1; b1 = t ? v : b1; i1 = t ? (int)w1.y : i1;
                    v = __uint_as_float(w1.z); bool u = v > b2; b2 = u ? v : b2; i2 = u ? (int)w1.w : i2;
                }
                {
                    float v = __uint_as_float(w2.x); bool t = v > b1; b1 = t ? v : b1; i1 = t ? (int)w2.y : i1;
                    v = __uint_as_float(w2.z); bool u = v > b2; b2 = u ? v : b2; i2 = u ? (int)w2.w : i2;
                }
                {
                    float v = __uint_as_float(w3.x); bool t = v > b1; b1 = t ? v : b1; i1 = t ? (int)w3.y : i1;
                    v = __uint_as_float(w3.z); bool u = v > b2; b2 = u ? v : b2; i2 = u ? (int)w3.w : i2;
                }

                float dmx = dp[i1],  cmx = cdp[i1];    // argmax of d*cd
                float dmn = dp[i2],  cmn = cdp[i2];    // argmax of cd/(d+eps)

                float mm_  = fabsf(dmn / (dmx + EPSF));
                float sfd  = (1.0f - a0 - a1) * mm_ + a0 * mm_ * mm_ + a1 * mm_ * mm_ * mm_;
                float csfd = cmx * cmn;
                float sv   = sp[m * 128 + n];
                float csv  = csp[m * 128 + n];
                float den  = wp * csv + csfd;
                float spv  = (wp * csv * sv + csfd * sfd) / (den + EPSF);
                float cp   = den / (wp + 1.0f);
                lx1[cmr][cn] = cp * spv;
                lx2[cmr][cn] = cp;
            }
        }
    }
    __syncthreads();

    // ---------------- stage D: deconv + epilogue (8 outputs/thread) ----------------
    int ii = tid >> 3, jq = tid & 7;
    int i  = ib + ii;
    int u0 = (i + 1) & 1;
    int m0 = (i + 1 - u0) >> 1;
    int pr0 = m0 - mB;                    // 1..17
    int pr1 = pr0 - 1;                    // 0..16
    float rv0 = (m0 <= 127) ? 1.f : 0.f;
    float rv1 = (m0 >= 1)   ? 1.f : 0.f;

    float wA0 = sws[u0*4 + 0], wA1 = sws[u0*4 + 1], wA2 = sws[u0*4 + 2], wA3 = sws[u0*4 + 3];
    float wC0 = sws[(u0+2)*4 + 0], wC1 = sws[(u0+2)*4 + 1], wC2 = sws[(u0+2)*4 + 2], wC3 = sws[(u0+2)*4 + 3];
    float bv  = bias[c];

    int bb = 4 * jq;                      // lx col base (6 cols used)
    float r1a[6], r1b[6], r2a[6], r2b[6];
    {
        const float* p = &lx1[pr0][bb];
        float4 t4 = *(const float4*)p;  float2 t2 = *(const float2*)(p + 4);
        r1a[0]=t4.x; r1a[1]=t4.y; r1a[2]=t4.z; r1a[3]=t4.w; r1a[4]=t2.x; r1a[5]=t2.y;
    }
    {
        const float* p = &lx1[pr1][bb];
        float4 t4 = *(const float4*)p;  float2 t2 = *(const float2*)(p + 4);
        r1b[0]=t4.x; r1b[1]=t4.y; r1b[2]=t4.z; r1b[3]=t4.w; r1b[4]=t2.x; r1b[5]=t2.y;
    }
    {
        const float* p = &lx2[pr0][bb];
        float4 t4 = *(const float4*)p;  float2 t2 = *(const float2*)(p + 4);
        r2a[0]=t4.x; r2a[1]=t4.y; r2a[2]=t4.z; r2a[3]=t4.w; r2a[4]=t2.x; r2a[5]=t2.y;
    }
    {
        const float* p = &lx2[pr1][bb];
        float4 t4 = *(const float4*)p;  float2 t2 = *(const float2*)(p + 4);
        r2b[0]=t4.x; r2b[1]=t4.y; r2b[2]=t4.z; r2b[3]=t4.w; r2b[4]=t2.x; r2b[5]=t2.y;
    }

    int n0b = (jb >> 1) + 4 * jq;
    size_t orow = (size_t)bc * 65536 + (size_t)i * 256 + jb + 8 * jq;

    float so[4], co[4];
    #pragma unroll
    for (int e = 0; e < 8; ++e) {
        const int v0 = (e + 1) & 1;
        const int hi = 1 + ((e + 1) >> 1);
        const int lo = hi - 1;
        float swa = v0 ? wA1 : wA0;       // (u0,   v0)
        float swb = v0 ? wA3 : wA2;       // (u0,   v0+2)
        float swc = v0 ? wC1 : wC0;       // (u0+2, v0)
        float swd = v0 ? wC3 : wC2;       // (u0+2, v0+2)

        float nom = swa*r1a[hi] + swb*r1a[lo] + swc*r1b[hi] + swd*r1b[lo];
        float den = swa*r2a[hi] + swb*r2a[lo] + swc*r2b[hi] + swd*r2b[lo];

        int n0 = n0b + ((e + 1) >> 1);
        float nvh = (n0 <= 127) ? 1.f : 0.f;
        float nvl = (n0 >= 1)   ? 1.f : 0.f;
        float cden = rv0 * (swa*nvh + swb*nvl) + rv1 * (swc*nvh + swd*nvl);

        so[e & 3] = nom / (den + EPSF) + bv;
        co[e & 3] = den / cden;
        if ((e & 3) == 3) {
            *(float4*)(s_out  + orow + (e - 3)) = make_float4(so[0], so[1], so[2], so[3]);
            *(float4*)(cs_out + orow + (e - 3)) = make_float4(co[0], co[1], co[2], co[3]);
        }
    }
}

extern "C" void kernel_launch(void* const* d_in, const int* in_sizes, int n_in,
                              void* d_out, int out_size, void* d_ws, size_t ws_size,
                              hipStream_t stream) {
    const float* d    = (const float*)d_in[0];
    const float* cd   = (const float*)d_in[1];
    const float* s    = (const float*)d_in[2];
    const float* cs   = (const float*)d_in[3];
    const float* wsd  = (const float*)d_in[4];
    const float* wpr  = (const float*)d_in[5];
    const float* spw  = (const float*)d_in[6];
    const float* bias = (const float*)d_in[7];

    float* out  = (float*)d_out;
    float* s_o  = out;
    float* cs_o = out + (size_t)4 * 16 * 256 * 256;

    // 64 planes x 32 tiles (8x4 of 32x64 outputs) = 2048 blocks
    fused_sndeconv<<<2048, 256, 0, stream>>>(d, cd, s, cs, wsd, wpr, spw, bias, s_o, cs_o);
}

// Round 5
// 29.785 us; speedup vs baseline: 1.5153x; 1.1882x over previous
//
#include <hip/hip_runtime.h>
#include <math.h>

#define EPSF 1e-20f
#define NEG_INF (-INFINITY)

__device__ __forceinline__ float softplusf(float x) {
    return fmaxf(x, 0.0f) + log1pf(expf(-fabsf(x)));
}
// fast reciprocal (v_rcp_f32, ~1ulp) — ONLY for tolerance-protected epilogue
// math, never for argmax comparison values.
__device__ __forceinline__ float fastrcp(float x) {
    return __builtin_amdgcn_rcpf(x);
}

// One block = 32x64 output tile of one (b,c) plane. 2048 blocks.
// Stage B: horizontal 4-col dual argmax per (input row, x-col); stores the
//          winners' VALUES (v1,d1,c1 / v2,d2,c2) in LDS — no index gathers.
// Stage C: vertical 4-row combine + propagation math -> lx LDS.
// Stage D: 4-tap transposed depthwise conv + fused epilogue.
__global__ __launch_bounds__(256) void fused_sndeconv(
    const float* __restrict__ d, const float* __restrict__ cd,
    const float* __restrict__ s, const float* __restrict__ cs,
    const float* __restrict__ w_s_from_d, const float* __restrict__ w_prop,
    const float* __restrict__ spatial_weight, const float* __restrict__ bias,
    float* __restrict__ s_out, float* __restrict__ cs_out)
{
    __shared__ float4 W4[38][34];        // (v1, d1, c1, v2)  20.7 KB
    __shared__ float2 W2[38][34];        // (d2, c2)          10.3 KB
    __shared__ float  lx1[18][36];       //  2.6 KB
    __shared__ float  lx2[18][36];
    __shared__ float  sws[16];

    const int tid = threadIdx.x;
    const int blk = blockIdx.x;
    const int bc  = blk >> 5;            // plane 0..63
    const int tl  = blk & 31;
    const int by  = tl >> 2;             // 0..7  (32-row bands)
    const int bx  = tl & 3;              // 0..3  (64-col bands)
    const int c   = bc & 15;

    const int ib = by << 5;              // output row base
    const int jb = bx << 6;              // output col base
    const int mB = (ib >> 1) - 1;        // x-row base (18 rows)
    const int nB = (jb >> 1) - 1;        // x-col base (34 cols)
    const int rB = 2 * mB - 1;           // input row base (38 rows)
    const int cB = 2 * nB - 1;           // input col base (odd)

    if (tid < 16) sws[tid] = softplusf(spatial_weight[c * 16 + tid]);

    const float* dp  = d  + (size_t)bc * 65536;
    const float* cdp = cd + (size_t)bc * 65536;
    const float* sp  = s  + (size_t)bc * 16384;
    const float* csp = cs + (size_t)bc * 16384;

    const float a0 = w_s_from_d[0];
    const float a1 = w_s_from_d[1];
    const float wp = softplusf(w_prop[0]);
    const float rwp1 = fastrcp(wp + 1.0f);

    // ---------------- stage B: horizontal window argmax ----------------
    #pragma unroll
    for (int it = 0; it < 6; ++it) {
        int unit = tid + 256 * it;
        if (unit < 1292) {
            int wr = unit / 34;
            int wn = unit - wr * 34;
            int r  = rB + wr;
            int cb = cB + 2 * wn;                    // odd
            bool rv = (r >= 0) && (r < 256);
            int  rl = r < 0 ? 0 : (r > 255 ? 255 : r);
            const float* drow = dp  + rl * 256;
            const float* crow = cdp + rl * 256;

            int c0 = cb < 0 ? 0 : cb;
            int c3 = (cb + 3 > 255) ? 255 : cb + 3;
            int cm = cb + 1; cm = cm < 0 ? 0 : (cm > 254 ? 254 : cm);  // even
            float2 dm = *(const float2*)(drow + cm);
            float2 cc = *(const float2*)(crow + cm);
            float wd[4] = { drow[c0], dm.x, dm.y, drow[c3] };
            float wc[4] = { crow[c0], cc.x, cc.y, crow[c3] };

            float b1 = NEG_INF, d1 = 0.f, c1 = 0.f;
            float b2 = NEG_INF, d2 = 0.f, c2 = 0.f;
            #pragma unroll
            for (int k = 0; k < 4; ++k) {
                int  ck = cb + k;
                bool mv = rv && (ck >= 0) && (ck < 256);
                float v1 = mv ? wd[k] * wc[k]          : NEG_INF;
                float v2 = mv ? wc[k] / (wd[k] + EPSF) : NEG_INF;  // EXACT div
                bool t1 = v1 > b1;
                b1 = t1 ? v1 : b1; d1 = t1 ? wd[k] : d1; c1 = t1 ? wc[k] : c1;
                bool t2 = v2 > b2;
                b2 = t2 ? v2 : b2; d2 = t2 ? wd[k] : d2; c2 = t2 ? wc[k] : c2;
            }
            W4[wr][wn] = make_float4(b1, d1, c1, b2);
            W2[wr][wn] = make_float2(d2, c2);
        }
    }
    __syncthreads();

    // ---------------- stage C: vertical combine + prop math ----------------
    #pragma unroll
    for (int it = 0; it < 3; ++it) {
        int unit = tid + 256 * it;
        if (unit < 612) {
            int cmr = unit / 34;
            int cn  = unit - cmr * 34;
            int m   = mB + cmr;
            int n   = nB + cn;
            if (m < 0 || m > 127 || n < 0 || n > 127) {
                lx1[cmr][cn] = 0.f;
                lx2[cmr][cn] = 0.f;
            } else {
                float4 a4 = W4[2 * cmr + 0][cn];  float2 a2 = W2[2 * cmr + 0][cn];
                float b1 = a4.x, d1 = a4.y, c1 = a4.z;
                float b2 = a4.w, d2 = a2.x, c2 = a2.y;
                #pragma unroll
                for (int k = 1; k < 4; ++k) {
                    float4 w4 = W4[2 * cmr + k][cn];
                    float2 w2 = W2[2 * cmr + k][cn];
                    bool t1 = w4.x > b1;
                    b1 = t1 ? w4.x : b1; d1 = t1 ? w4.y : d1; c1 = t1 ? w4.z : c1;
                    bool t2 = w4.w > b2;
                    b2 = t2 ? w4.w : b2; d2 = t2 ? w2.x : d2; c2 = t2 ? w2.y : c2;
                }

                float mm_  = fabsf(d2 * fastrcp(d1 + EPSF));
                float sfd  = (1.0f - a0 - a1) * mm_ + a0 * mm_ * mm_ + a1 * mm_ * mm_ * mm_;
                float csfd = c1 * c2;
                float sv   = sp[m * 128 + n];
                float csv  = csp[m * 128 + n];
                float den  = wp * csv + csfd;
                float spv  = (wp * csv * sv + csfd * sfd) * fastrcp(den + EPSF);
                float cp   = den * rwp1;
                lx1[cmr][cn] = cp * spv;
                lx2[cmr][cn] = cp;
            }
        }
    }
    __syncthreads();

    // ---------------- stage D: deconv + epilogue (8 outputs/thread) ----------------
    int ii = tid >> 3, jq = tid & 7;
    int i  = ib + ii;
    int u0 = (i + 1) & 1;
    int m0 = (i + 1 - u0) >> 1;
    int pr0 = m0 - mB;                    // 1..17
    int pr1 = pr0 - 1;                    // 0..16
    float rv0 = (m0 <= 127) ? 1.f : 0.f;
    float rv1 = (m0 >= 1)   ? 1.f : 0.f;

    float wA0 = sws[u0*4 + 0], wA1 = sws[u0*4 + 1], wA2 = sws[u0*4 + 2], wA3 = sws[u0*4 + 3];
    float wC0 = sws[(u0+2)*4 + 0], wC1 = sws[(u0+2)*4 + 1], wC2 = sws[(u0+2)*4 + 2], wC3 = sws[(u0+2)*4 + 3];
    float bv  = bias[c];

    int bb = 4 * jq;
    float r1a[6], r1b[6], r2a[6], r2b[6];
    {
        const float* p = &lx1[pr0][bb];
        float4 t4 = *(const float4*)p;  float2 t2 = *(const float2*)(p + 4);
        r1a[0]=t4.x; r1a[1]=t4.y; r1a[2]=t4.z; r1a[3]=t4.w; r1a[4]=t2.x; r1a[5]=t2.y;
    }
    {
        const float* p = &lx1[pr1][bb];
        float4 t4 = *(const float4*)p;  float2 t2 = *(const float2*)(p + 4);
        r1b[0]=t4.x; r1b[1]=t4.y; r1b[2]=t4.z; r1b[3]=t4.w; r1b[4]=t2.x; r1b[5]=t2.y;
    }
    {
        const float* p = &lx2[pr0][bb];
        float4 t4 = *(const float4*)p;  float2 t2 = *(const float2*)(p + 4);
        r2a[0]=t4.x; r2a[1]=t4.y; r2a[2]=t4.z; r2a[3]=t4.w; r2a[4]=t2.x; r2a[5]=t2.y;
    }
    {
        const float* p = &lx2[pr1][bb];
        float4 t4 = *(const float4*)p;  float2 t2 = *(const float2*)(p + 4);
        r2b[0]=t4.x; r2b[1]=t4.y; r2b[2]=t4.z; r2b[3]=t4.w; r2b[4]=t2.x; r2b[5]=t2.y;
    }

    int n0b = (jb >> 1) + 4 * jq;
    size_t orow = (size_t)bc * 65536 + (size_t)i * 256 + jb + 8 * jq;

    float so[4], co[4];
    #pragma unroll
    for (int e = 0; e < 8; ++e) {
        const int v0 = (e + 1) & 1;
        const int hi = 1 + ((e + 1) >> 1);
        const int lo = hi - 1;
        float swa = v0 ? wA1 : wA0;       // (u0,   v0)
        float swb = v0 ? wA3 : wA2;       // (u0,   v0+2)
        float swc = v0 ? wC1 : wC0;       // (u0+2, v0)
        float swd = v0 ? wC3 : wC2;       // (u0+2, v0+2)

        float nom = swa*r1a[hi] + swb*r1a[lo] + swc*r1b[hi] + swd*r1b[lo];
        float den = swa*r2a[hi] + swb*r2a[lo] + swc*r2b[hi] + swd*r2b[lo];

        int n0 = n0b + ((e + 1) >> 1);
        float nvh = (n0 <= 127) ? 1.f : 0.f;
        float nvl = (n0 >= 1)   ? 1.f : 0.f;
        float cden = rv0 * (swa*nvh + swb*nvl) + rv1 * (swc*nvh + swd*nvl);

        so[e & 3] = nom * fastrcp(den + EPSF) + bv;
        co[e & 3] = den * fastrcp(cden);
        if ((e & 3) == 3) {
            *(float4*)(s_out  + orow + (e - 3)) = make_float4(so[0], so[1], so[2], so[3]);
            *(float4*)(cs_out + orow + (e - 3)) = make_float4(co[0], co[1], co[2], co[3]);
        }
    }
}

extern "C" void kernel_launch(void* const* d_in, const int* in_sizes, int n_in,
                              void* d_out, int out_size, void* d_ws, size_t ws_size,
                              hipStream_t stream) {
    const float* d    = (const float*)d_in[0];
    const float* cd   = (const float*)d_in[1];
    const float* s    = (const float*)d_in[2];
    const float* cs   = (const float*)d_in[3];
    const float* wsd  = (const float*)d_in[4];
    const float* wpr  = (const float*)d_in[5];
    const float* spw  = (const float*)d_in[6];
    const float* bias = (const float*)d_in[7];

    float* out  = (float*)d_out;
    float* s_o  = out;
    float* cs_o = out + (size_t)4 * 16 * 256 * 256;

    // 64 planes x 32 tiles (8x4 of 32x64 outputs) = 2048 blocks
    fused_sndeconv<<<2048, 256, 0, stream>>>(d, cd, s, cs, wsd, wpr, spw, bias, s_o, cs_o);
}